// Round 1
// baseline (2733.561 us; speedup 1.0000x reference)
//
#include <hip/hip_runtime.h>
#include <cstdint>
#include <cstddef>

// HardNegativeMining: B=2048 rows, N=100000 candidates, k=128 outputs/row.
// out_logits[row] = [logits[pos], top-127 of remaining logits desc]
// out_labels[row] = [1, 0, ..., 0]
// Strategy: threshold-scan (z=2.5 -> ~621 cand/row iid-normal) + small sort.
// Fully general slow path covers pathological rows (never triggers on bench data).

#define N_CAND 100000
#define KOUT 128
#define THRESH 2.5f
#define SORT_N 1024  // LDS sort size (pow2), also max candidate capacity

// ---------------- Kernel 1: fused streaming scan of logits + labels ----------------
__global__ __launch_bounds__(256) void hnm_scan(
    const float* __restrict__ logits,
    const float* __restrict__ labels,
    int* __restrict__ cnt,
    int* __restrict__ posArr,
    uint2* __restrict__ cand,
    int cap)
{
    const int row = blockIdx.y;
    const int t   = blockIdx.x * 256 + threadIdx.x;
    const int col = t * 4;
    const bool inb = (col < N_CAND);  // N_CAND % 4 == 0, so float4 is all-or-nothing

    float4 lg = make_float4(-1e30f, -1e30f, -1e30f, -1e30f);
    float4 lb = make_float4(0.f, 0.f, 0.f, 0.f);
    if (inb) {
        lg = ((const float4*)(logits + (size_t)row * N_CAND))[t];
        lb = ((const float4*)(labels + (size_t)row * N_CAND))[t];
    }

    // Positive detection: exactly one nonzero label per row -> one writer, plain store.
    if (lb.x != 0.f) posArr[row] = col + 0;
    if (lb.y != 0.f) posArr[row] = col + 1;
    if (lb.z != 0.f) posArr[row] = col + 2;
    if (lb.w != 0.f) posArr[row] = col + 3;

    float v[4] = {lg.x, lg.y, lg.z, lg.w};
    int c = (v[0] > THRESH) + (v[1] > THRESH) + (v[2] > THRESH) + (v[3] > THRESH);

    // Wave-aggregated append: 1 atomic per wave that has any candidate (~80% of waves).
    unsigned long long ball = __ballot(c > 0);
    if (ball == 0ull) return;

    const int lane = threadIdx.x & 63;
    int pre = c;  // inclusive prefix over the wave
    #pragma unroll
    for (int d = 1; d < 64; d <<= 1) {
        int o = __shfl_up(pre, d, 64);
        if (lane >= d) pre += o;
    }
    int total = __shfl(pre, 63, 64);
    int base = 0;
    if (lane == 63) base = atomicAdd(&cnt[row], total);
    base = __shfl(base, 63, 64);

    int off = base + pre - c;  // exclusive prefix
    #pragma unroll
    for (int j = 0; j < 4; ++j) {
        if (v[j] > THRESH) {
            if (off < cap) {
                uint2 e;
                e.x = __float_as_uint(v[j]);
                e.y = (unsigned)(col + j);
                cand[(size_t)row * cap + off] = e;
            }
            off++;
        }
    }
}

// ---------------- Kernel 2: per-row top-127 negatives + emit ----------------
__global__ __launch_bounds__(256) void hnm_topk(
    const float* __restrict__ logits,
    const int* __restrict__ cnt,
    const int* __restrict__ posArr,
    const uint2* __restrict__ cand,
    int cap,
    float* __restrict__ outLogits,
    float* __restrict__ outLabels)
{
    __shared__ float sv[SORT_N];
    __shared__ float swv[4];
    __shared__ int   swi[4];
    __shared__ float sbv;
    __shared__ int   sbi;

    const int row = blockIdx.x;
    const int tid = threadIdx.x;

    int count = cnt[row];
    int pos   = posArr[row];
    if ((unsigned)pos >= (unsigned)N_CAND) pos = 0;  // safety (all-zero labels)

    const float posVal = logits[(size_t)row * N_CAND + pos];
    float* oL = outLogits + (size_t)row * KOUT;
    float* oB = outLabels + (size_t)row * KOUT;

    if (count >= KOUT && count <= cap) {
        // ---- fast path: candidates hold every value > THRESH; >=127 negatives among them
        for (int i = tid; i < SORT_N; i += 256) {
            float v = -INFINITY;
            if (i < count) {
                uint2 e = cand[(size_t)row * cap + i];
                v = __uint_as_float(e.x);
                if ((int)e.y == pos) v = -INFINITY;  // exclude the positive
            }
            sv[i] = v;
        }
        __syncthreads();

        // bitonic sort, descending
        for (int k = 2; k <= SORT_N; k <<= 1) {
            for (int j = k >> 1; j > 0; j >>= 1) {
                for (int i = tid; i < SORT_N; i += 256) {
                    int ixj = i ^ j;
                    if (ixj > i) {
                        float a = sv[i], b = sv[ixj];
                        bool up = ((i & k) == 0);
                        if (up ? (a < b) : (a > b)) { sv[i] = b; sv[ixj] = a; }
                    }
                }
                __syncthreads();
            }
        }

        if (tid < KOUT) {
            oL[tid] = (tid == 0) ? posVal : sv[tid - 1];
            oB[tid] = (tid == 0) ? 1.0f : 0.0f;
        }
    } else {
        // ---- slow path (general correctness; never hit on iid-normal bench data):
        // 127 rounds of block-wide lexicographic max over the raw row.
        if (tid < KOUT) oB[tid] = (tid == 0) ? 1.0f : 0.0f;
        if (tid == 0)   oL[0]  = posVal;

        const float* rowp = logits + (size_t)row * N_CAND;
        float prevV = INFINITY;
        int   prevI = -1;
        const int wid  = tid >> 6;
        const int lane = tid & 63;

        for (int r = 0; r < KOUT - 1; ++r) {
            float bv = -INFINITY;
            int   bi = 0x7fffffff;
            for (int i = tid; i < N_CAND; i += 256) {
                if (i == pos) continue;
                float v = rowp[i];
                bool elig = (v < prevV) || (v == prevV && i > prevI);
                if (elig && (v > bv || (v == bv && i < bi))) { bv = v; bi = i; }
            }
            #pragma unroll
            for (int d = 32; d > 0; d >>= 1) {
                float ov = __shfl_down(bv, d, 64);
                int   oi = __shfl_down(bi, d, 64);
                if (ov > bv || (ov == bv && oi < bi)) { bv = ov; bi = oi; }
            }
            if (lane == 0) { swv[wid] = bv; swi[wid] = bi; }
            __syncthreads();
            if (tid == 0) {
                #pragma unroll
                for (int w = 1; w < 4; ++w) {
                    if (swv[w] > bv || (swv[w] == bv && swi[w] < bi)) { bv = swv[w]; bi = swi[w]; }
                }
                sbv = bv; sbi = bi;
                oL[1 + r] = bv;
            }
            __syncthreads();
            prevV = sbv;
            prevI = sbi;
        }
    }
}

extern "C" void kernel_launch(void* const* d_in, const int* in_sizes, int n_in,
                              void* d_out, int out_size, void* d_ws, size_t ws_size,
                              hipStream_t stream) {
    const float* logits = (const float*)d_in[0];
    const float* labels = (const float*)d_in[1];
    const int B = in_sizes[0] / N_CAND;  // 2048

    float* outLogits = (float*)d_out;
    float* outLabels = outLogits + (size_t)B * KOUT;

    // Workspace layout: [cnt: B ints][pos: B ints][cand: B*cap uint2]
    int*  cnt    = (int*)d_ws;
    int*  posArr = cnt + B;
    uint2* cand  = (uint2*)(posArr + B);
    size_t fixed = (size_t)B * 8;
    size_t avail = (ws_size > fixed) ? (ws_size - fixed) : 0;
    size_t cap_sz = avail / ((size_t)B * sizeof(uint2));
    int cap = (int)(cap_sz > (size_t)SORT_N ? (size_t)SORT_N : cap_sz);

    // counters + pos must be zeroed every launch (ws is re-poisoned to 0xAA)
    hipMemsetAsync(d_ws, 0, fixed, stream);

    dim3 g1((N_CAND / 4 + 255) / 256, B);  // 98 x 2048 blocks
    hnm_scan<<<g1, 256, 0, stream>>>(logits, labels, cnt, posArr, cand, cap);
    hnm_topk<<<B, 256, 0, stream>>>(logits, cnt, posArr, cand, cap, outLogits, outLabels);
}